// Round 20
// baseline (184.746 us; speedup 1.0000x reference)
//
#include <hip/hip_runtime.h>

// Pipeline (r18-verified numerics; only change: flash QK^T setprio hoisted to
// bracket the whole MFMA cluster — value-neutral scheduling hint):
//  1. split_x:          x f32 [4096,1024] -> x_hi, x_lo bf16
//  2. transpose_split:  w_qkv f32 [1024,3072] -> w_hi_t, w_lo_t bf16 [3072,1024] (N-major)
//  3. transpose_split:  w_out f32 [1024,1024] -> w_out_t bf16 [1024,1024]
//  3b. rope_tab:        cos/sin tables [2048][32] f32 -> scratch carved from d_out
//  4. gemm_qkv:   128x128xBK32 dbuf gload_lds pipeline, 512 threads / 8 waves,
//                 balanced 1D grid (Q|K|V), fused RoPE epilogue, V^T output.
//  5. flash:      causal attention; 128-row strips, pair-balanced LPT, 8 waves x 16 rows,
//                 dbuf K/V LDS, V^T staged like K, defer-max (THR=8), ones-MFMA row-sum,
//                 RTE f2bf P pack (trunc-P NaNs — do not reintroduce).
//  6. gemm_out:   BK=32 dbuf, 256 threads.

typedef __attribute__((ext_vector_type(8))) short s16x8;
typedef __attribute__((ext_vector_type(8))) unsigned short u16x8;
typedef __attribute__((ext_vector_type(4))) float f32x4;
typedef __attribute__((ext_vector_type(4))) int i32x4;

#define L2E 1.44269504088896340736f

__device__ __forceinline__ unsigned short f2bf(float f) {
  unsigned int u = __builtin_bit_cast(unsigned int, f);
  u += 0x7FFFu + ((u >> 16) & 1u);
  return (unsigned short)(u >> 16);
}
__device__ __forceinline__ float bf2f(unsigned short h) {
  unsigned int u = ((unsigned int)h) << 16;
  return __builtin_bit_cast(float, u);
}

__device__ __forceinline__ void gload16(const void* g, void* l) {
  __builtin_amdgcn_global_load_lds(
      (const __attribute__((address_space(1))) unsigned int*)g,
      (__attribute__((address_space(3))) unsigned int*)l, 16, 0, 0);
}

// ---------------- 1. split x into hi/lo bf16 ----------------
__global__ __launch_bounds__(256) void split_x_kernel(
    const float* __restrict__ x, unsigned short* __restrict__ xhi,
    unsigned short* __restrict__ xlo) {
  size_t i = ((size_t)blockIdx.x * 256 + threadIdx.x) * 8;
  f32x4 a = *(const f32x4*)(x + i);
  f32x4 c = *(const f32x4*)(x + i + 4);
  u16x8 h, lo;
#pragma unroll
  for (int j = 0; j < 4; ++j) {
    unsigned short hv = f2bf(a[j]);
    h[j] = hv; lo[j] = f2bf(a[j] - bf2f(hv));
    unsigned short hv2 = f2bf(c[j]);
    h[4 + j] = hv2; lo[4 + j] = f2bf(c[j] - bf2f(hv2));
  }
  *(u16x8*)(xhi + i) = h;
  *(u16x8*)(xlo + i) = lo;
}

// ---------------- 2/3. transpose + split weights ----------------
__global__ __launch_bounds__(256) void transpose_split_kernel(
    const float* __restrict__ W, unsigned short* __restrict__ Thi,
    unsigned short* __restrict__ Tlo, int N, int hasLo) {
  __shared__ unsigned short hi[64][72];
  __shared__ unsigned short lo[64][72];
  const int t = threadIdx.x;
  const int k0 = blockIdx.x * 64, n0 = blockIdx.y * 64;
#pragma unroll
  for (int r = 0; r < 16; ++r) {
    int kk = r * 4 + (t >> 6);
    int nn = t & 63;
    float v = W[(size_t)(k0 + kk) * N + n0 + nn];
    unsigned short hv = f2bf(v);
    hi[nn][kk] = hv;
    lo[nn][kk] = f2bf(v - bf2f(hv));
  }
  __syncthreads();
#pragma unroll
  for (int i = 0; i < 2; ++i) {
    int ci = t + i * 256;
    int nn = ci >> 3, kc = (ci & 7) * 8;
    u16x8 vh, vl;
#pragma unroll
    for (int j = 0; j < 8; ++j) { vh[j] = hi[nn][kc + j]; vl[j] = lo[nn][kc + j]; }
    *(u16x8*)(Thi + (size_t)(n0 + nn) * 1024 + k0 + kc) = vh;
    if (hasLo) *(u16x8*)(Tlo + (size_t)(n0 + nn) * 1024 + k0 + kc) = vl;
  }
}

// ---------------- 3b. RoPE cos/sin tables ----------------
__global__ __launch_bounds__(256) void rope_tab_kernel(float* __restrict__ tab) {
  int idx = blockIdx.x * 256 + threadIdx.x;  // 0..65535
  int s = idx >> 5, i = idx & 31;
  float invf = exp2f(-(float)i * 0.4152410118609203f);  // 10000^(-i/32)
  float ang = (float)s * invf;
  tab[idx] = cosf(ang);
  tab[65536 + idx] = sinf(ang);
}

// ---------------- 4. QKV GEMM: 512 threads, 8 waves, BK=32 dbuf ----------------
__global__ __launch_bounds__(512, 4) void gemm_qkv_kernel(
    const unsigned short* __restrict__ xhi, const unsigned short* __restrict__ xlo,
    const unsigned short* __restrict__ whi, const unsigned short* __restrict__ wlo,
    const float* __restrict__ bqkv, const float* __restrict__ ctab,
    unsigned short* __restrict__ Qsb, unsigned short* __restrict__ Ksb,
    unsigned short* __restrict__ vbufT) {
  __shared__ alignas(16) unsigned short sh[32768];
  const int tid = threadIdx.x, w = tid >> 6, l = tid & 63;
  const int l15 = l & 15, l4 = l >> 4;
  const int sid = blockIdx.x;           // 0..767
  const int m0 = (sid & 31) * 128;
  const int n0 = (sid >> 5) * 128;      // 0..2944
  const int wrow = w >> 1, wcol = w & 1;
  const int which = n0 >> 10;           // 0=Q 1=K 2=V (block-uniform)
  const bool isV = (which == 2);
  const float* stab = ctab + 65536;

  f32x4 acc[2][4] = {};

#define STAGEP(p_) do {                                                        \
    int kk_ = (p_) * 32;                                                       \
    unsigned short* bb_ = sh + (((p_) & 1) << 14);                             \
    _Pragma("unroll")                                                          \
    for (int i = 0; i < 4; ++i) {                                              \
      int c_ = w * 4 + i;                                                      \
      if (isV && c_ >= 16) break;                                              \
      int arr_ = c_ >> 3, rc_ = c_ & 7;                                        \
      int row_ = rc_ * 16 + (l >> 2);                                          \
      const unsigned short* src_;                                              \
      if (arr_ == 0)      src_ = xhi + (size_t)(m0 + row_) * 1024;             \
      else if (arr_ == 1) src_ = whi + (size_t)(n0 + row_) * 1024;             \
      else if (arr_ == 2) src_ = wlo + (size_t)(n0 + row_) * 1024;             \
      else                src_ = xlo + (size_t)(m0 + row_) * 1024;             \
      gload16(src_ + kk_ + (l & 3) * 8, bb_ + arr_ * 4096 + rc_ * 512);        \
    }                                                                          \
  } while (0)

  STAGEP(0);
  __syncthreads();
  for (int p = 0; p < 32; ++p) {
    if (p + 1 < 32) STAGEP(p + 1);     // async into buf^1, overlaps compute below
    const unsigned short* bp = sh + ((p & 1) << 14);
    s16x8 af[2], bfr[4];
#pragma unroll
    for (int g = 0; g < 2; ++g)
      af[g] = *(const s16x8*)(bp + (wrow * 32 + g * 16 + l15) * 32 + l4 * 8);
#pragma unroll
    for (int cg = 0; cg < 4; ++cg)
      bfr[cg] = *(const s16x8*)(bp + 4096 + (wcol * 64 + cg * 16 + l15) * 32 + l4 * 8);
#pragma unroll
    for (int rg = 0; rg < 2; ++rg)
#pragma unroll
      for (int cg = 0; cg < 4; ++cg)
        acc[rg][cg] = __builtin_amdgcn_mfma_f32_16x16x32_bf16(af[rg], bfr[cg], acc[rg][cg], 0, 0, 0);
    if (!isV) {
      s16x8 bl[4], al[2];
#pragma unroll
      for (int cg = 0; cg < 4; ++cg)
        bl[cg] = *(const s16x8*)(bp + 8192 + (wcol * 64 + cg * 16 + l15) * 32 + l4 * 8);
#pragma unroll
      for (int g = 0; g < 2; ++g)
        al[g] = *(const s16x8*)(bp + 12288 + (wrow * 32 + g * 16 + l15) * 32 + l4 * 8);
#pragma unroll
      for (int rg = 0; rg < 2; ++rg)
#pragma unroll
        for (int cg = 0; cg < 4; ++cg)
          acc[rg][cg] = __builtin_amdgcn_mfma_f32_16x16x32_bf16(af[rg], bl[cg], acc[rg][cg], 0, 0, 0);
#pragma unroll
      for (int rg = 0; rg < 2; ++rg)
#pragma unroll
        for (int cg = 0; cg < 4; ++cg)
          acc[rg][cg] = __builtin_amdgcn_mfma_f32_16x16x32_bf16(al[rg], bfr[cg], acc[rg][cg], 0, 0, 0);
    }
    __syncthreads();
  }
#undef STAGEP

  // ------- epilogue (LDS transpose -> coalesced stores), 512 threads -------
  const int n_head0 = (n0 & 1023) >> 6;
  const int bb = m0 >> 11;
  const int s_base = m0 & 2047;
  unsigned short* stg = sh;

  if (isV) {
#pragma unroll
    for (int cg = 0; cg < 4; ++cg) {
      int n_local = wcol * 64 + cg * 16 + l15;
      float bias = bqkv[n0 + n_local];
      int swz = (n_local & 7) << 3;
#pragma unroll
      for (int rg = 0; rg < 2; ++rg)
#pragma unroll
        for (int r = 0; r < 4; ++r) {
          int m_local = wrow * 32 + rg * 16 + l4 * 4 + r;
          stg[n_local * 128 + (m_local ^ swz)] = f2bf(acc[rg][cg][r] + bias);
        }
    }
    __syncthreads();
#pragma unroll
    for (int i = 0; i < 4; ++i) {
      int c = i * 512 + tid;
      int n = c >> 4, piece = c & 15;
      int hh = n_head0 + (n >> 6), d = n & 63;
      unsigned short* dst =
          vbufT + ((size_t)(bb * 16 + hh)) * 131072 + d * 2048 + s_base + piece * 8;
      *(i32x4*)dst = *(const i32x4*)(stg + n * 128 + ((piece * 8) ^ ((n & 7) << 3)));
    }
  } else {
    unsigned short* qk = which ? Ksb : Qsb;
    const float sc8 = which ? 1.0f : 8.0f;
#pragma unroll
    for (int cg = 0; cg < 4; ++cg) {
      int n_local = wcol * 64 + cg * 16 + l15;
      int dk = n_local & 63;
      int ih = dk >> 1;
      float bias = bqkv[n0 + n_local];
#pragma unroll
      for (int rg = 0; rg < 2; ++rg)
#pragma unroll
        for (int r = 0; r < 4; ++r) {
          int s = s_base + wrow * 32 + rg * 16 + l4 * 4 + r;
          float v = acc[rg][cg][r] + bias;
          float p = __shfl_xor(v, 1);
          float cs = ctab[(s << 5) + ih];
          float sn = stab[(s << 5) + ih];
          float rr = (dk & 1) ? (p * sn + v * cs) : (v * cs - p * sn);
          acc[rg][cg][r] = rr * sc8;
        }
    }
#pragma unroll
    for (int pass = 0; pass < 2; ++pass) {
#pragma unroll
      for (int cg = 0; cg < 4; ++cg) {
        int n_local = wcol * 64 + cg * 16 + l15;
#pragma unroll
        for (int rg = 0; rg < 2; ++rg)
#pragma unroll
          for (int r = 0; r < 4; ++r) {
            int m_local = wrow * 32 + rg * 16 + l4 * 4 + r;
            float rr = acc[rg][cg][r];
            unsigned short hv = f2bf(rr);
            stg[m_local * 128 + n_local] = pass ? f2bf(rr - bf2f(hv)) : hv;
          }
      }
      __syncthreads();
#pragma unroll
      for (int i = 0; i < 4; ++i) {
        int c = i * 512 + tid;
        int hh_l = c >> 10, row = (c >> 3) & 127, piece = c & 7;
        int hh = n_head0 + hh_l;
        unsigned short* dst =
            qk + (((size_t)bb * 16 + hh) * 2048 + s_base + row) * 128 + pass * 64;
        *(i32x4*)(dst + piece * 8) = *(const i32x4*)(stg + row * 128 + hh_l * 64 + piece * 8);
      }
      __syncthreads();
    }
  }
}

// ---------------- 5. flash: dbuf K/V LDS, ones-MFMA row-sum ----------------
__global__ __launch_bounds__(512, 4) void flash_kernel(
    const unsigned short* __restrict__ Qs, const unsigned short* __restrict__ Ks,
    const unsigned short* __restrict__ VbT, unsigned short* __restrict__ attn) {
  __shared__ alignas(16) unsigned short Khi[2][64 * 64];
  __shared__ alignas(16) unsigned short Klo[2][64 * 64];
  __shared__ alignas(16) unsigned short Vt[2][64 * 64];
  __shared__ alignas(16) unsigned short Pl[8][16 * 64];

  const int tid = threadIdx.x;
  const int wv = tid >> 6, l = tid & 63;
  const int l15 = l & 15, l4 = l >> 4;

  const int sid = blockIdx.x;            // 0..511
  const int idx = (sid & 255) >> 5;      // 0..7
  const int strip = (sid >> 8) ? idx : 15 - idx;
  const int hb = sid & 31;
  const int h = hb & 15, b = hb >> 4;
  const int qb = strip * 128;

  const size_t bh = (size_t)(b * 16 + h);
  const unsigned short* Qbase = Qs + bh * 2048 * 128;
  const unsigned short* Kbase = Ks + bh * 2048 * 128;
  const unsigned short* Vbase = VbT + bh * 131072;   // [64 d][2048 s]

  s16x8 qf[2][2];  // [hi/lo][ks]
  {
    int q = qb + wv * 16 + l15;
    const unsigned short* qr = Qbase + (size_t)q * 128;
#pragma unroll
    for (int ks = 0; ks < 2; ++ks) {
      qf[0][ks] = *(const s16x8*)(qr + ks * 32 + l4 * 8);
      qf[1][ks] = *(const s16x8*)(qr + 64 + ks * 32 + l4 * 8);
    }
  }

  s16x8 vones;
#pragma unroll
  for (int j = 0; j < 8; ++j) vones[j] = (short)0x3F80;

  f32x4 acc[4] = {};
  f32x4 accl = {};
  float mrow[4];
#pragma unroll
  for (int r = 0; r < 4; ++r) mrow[r] = -1e38f;

  const int row = tid >> 3;            // 0..63
  const int cb = (tid & 7) * 16;

  i32x4 kh, kl, vv;
#define PREF(kt_) do {                                                        \
    int kv0_ = (kt_) * 64;                                                    \
    const char* s_ = (const char*)(Kbase + (size_t)(kv0_ + row) * 128);       \
    kh = *(const i32x4*)(s_ + cb);  kl = *(const i32x4*)(s_ + 128 + cb);      \
    vv = *(const i32x4*)((const char*)(Vbase + (size_t)row * 2048 + kv0_) + cb); \
  } while (0)

#define STAGE(bf_) do {                                                       \
    int sw = cb ^ ((row & 7) << 4);                                           \
    *(i32x4*)((char*)Khi[bf_] + row * 128 + sw) = kh;                         \
    *(i32x4*)((char*)Klo[bf_] + row * 128 + sw) = kl;                         \
    *(i32x4*)((char*)Vt[bf_] + row * 128 + sw) = vv;                          \
  } while (0)

  const int nt = (qb >> 6) + 2;
  PREF(0);
  STAGE(0);
  if (nt > 1) PREF(1);
  __syncthreads();

  for (int kt = 0; kt < nt; ++kt) {
    const int kv0 = kt * 64;
    const int cur = kt & 1;
    if (kt + 1 < nt) {
      STAGE(cur ^ 1);
      if (kt + 2 < nt) PREF(kt + 2);
    }

    // S = (8 Q_roped) K_roped^T : 3-term split product (setprio brackets cluster)
    f32x4 sc[4];
    __builtin_amdgcn_s_setprio(1);
#pragma unroll
    for (int cg = 0; cg < 4; ++cg) {
      int kr = cg * 16 + l15;
      int swz = (kr & 7) << 4;
      const char* ph = (const char*)Khi[cur] + kr * 128;
      const char* pl2 = (const char*)Klo[cur] + kr * 128;
      s16x8 kbh[2], kbl[2];
#pragma unroll
      for (int ks = 0; ks < 2; ++ks) {
        int off = (ks * 64 + l4 * 16) ^ swz;
        kbh[ks] = *(const s16x8*)(ph + off);
        kbl[ks] = *(const s16x8*)(pl2 + off);
      }
      f32x4 a = {0.f, 0.f, 0.f, 0.f};
#pragma unroll
      for (int ks = 0; ks < 2; ++ks) {
        a = __builtin_amdgcn_mfma_f32_16x16x32_bf16(qf[0][ks], kbh[ks], a, 0, 0, 0);
        a = __builtin_amdgcn_mfma_f32_16x16x32_bf16(qf[0][ks], kbl[ks], a, 0, 0, 0);
        a = __builtin_amdgcn_mfma_f32_16x16x32_bf16(qf[1][ks], kbh[ks], a, 0, 0, 0);
      }
      sc[cg] = a;
    }
    __builtin_amdgcn_s_setprio(0);

    if (kt >= (qb >> 6)) {
#pragma unroll
      for (int cg = 0; cg < 4; ++cg)
#pragma unroll
        for (int r = 0; r < 4; ++r) {
          int q = qb + wv * 16 + l4 * 4 + r;
          int kv = kv0 + cg * 16 + l15;
          if (kv > q) sc[cg][r] = -1e38f;
        }
    }

    {
      float vmax[4];
      bool cnd = true;
#pragma unroll
      for (int r = 0; r < 4; ++r) {
        float v = fmaxf(fmaxf(sc[0][r], sc[1][r]), fmaxf(sc[2][r], sc[3][r]));
        v = fmaxf(v, __shfl_xor(v, 1));
        v = fmaxf(v, __shfl_xor(v, 2));
        v = fmaxf(v, __shfl_xor(v, 4));
        v = fmaxf(v, __shfl_xor(v, 8));
        vmax[r] = v;
        cnd = cnd && (v <= mrow[r] + 8.0f);
      }
      const bool defer = __all(cnd ? 1 : 0);
      if (!defer) {
#pragma unroll
        for (int r = 0; r < 4; ++r) {
          float mn = fmaxf(mrow[r], vmax[r]);
          float al = exp2f((mrow[r] - mn) * L2E);
          mrow[r] = mn;
          accl[r] *= al;
#pragma unroll
          for (int dg = 0; dg < 4; ++dg) acc[dg][r] *= al;
        }
      }
#pragma unroll
      for (int cg = 0; cg < 4; ++cg)
#pragma unroll
        for (int r = 0; r < 4; ++r)
          sc[cg][r] = exp2f((sc[cg][r] - mrow[r]) * L2E);
      // P pack: RTE f2bf (trunc variant NaNs — verified r17/r19; keep RTE)
#pragma unroll
      for (int cg = 0; cg < 4; ++cg)
#pragma unroll
        for (int r = 0; r < 4; ++r) {
          int roww = l4 * 4 + r;
          int colb = (cg * 16 + l15) * 2;
          int addr = roww * 128 + (colb ^ ((roww & 7) << 4));
          *(unsigned short*)((char*)Pl[wv] + addr) = f2bf(sc[cg][r]);
        }
    }

    {
      s16x8 pf[2];
      int swz = (l15 & 7) << 4;
#pragma unroll
      for (int kc = 0; kc < 2; ++kc)
        pf[kc] = *(const s16x8*)((const char*)Pl[wv] + l15 * 128 + ((kc * 64 + l4 * 16) ^ swz));
      __builtin_amdgcn_s_setprio(1);
#pragma unroll
      for (int dg = 0; dg < 4; ++dg) {
        int dr = dg * 16 + l15;
        int swzd = (dr & 7) << 4;
#pragma unroll
        for (int kc = 0; kc < 2; ++kc) {
          s16x8 vf = *(const s16x8*)((const char*)Vt[cur] + dr * 128 + ((kc * 64 + l4 * 16) ^ swzd));
          acc[dg] = __builtin_amdgcn_mfma_f32_16x16x32_bf16(pf[kc], vf, acc[dg], 0, 0, 0);
        }
      }
#pragma unroll
      for (int kc = 0; kc < 2; ++kc)
        accl = __builtin_amdgcn_mfma_f32_16x16x32_bf16(pf[kc], vones, accl, 0, 0, 0);
      __builtin_amdgcn_s_setprio(0);
    }
    __syncthreads();
  }
#undef PREF
#undef STAGE

  {
    unsigned short* stg = (unsigned short*)Pl;
#pragma unroll
    for (int r = 0; r < 4; ++r) {
      float inv = 1.0f / accl[r];
      int row_local = wv * 16 + l4 * 4 + r;
#pragma unroll
      for (int dg = 0; dg < 4; ++dg)
        stg[row_local * 64 + dg * 16 + l15] = f2bf(acc[dg][r] * inv);
    }
    __syncthreads();
#pragma unroll
    for (int i = 0; i < 2; ++i) {
      int c = i * 512 + tid;
      int rw = c >> 3, piece = c & 7;
      unsigned short* dst = attn + ((size_t)(b * 2048 + qb + rw)) * 1024 + h * 64;
      *(i32x4*)(dst + piece * 8) = *(const i32x4*)(stg + rw * 64 + piece * 8);
    }
  }
}

// ---------------- 6. output projection: BK=32 dbuf ----------------
__global__ __launch_bounds__(256) void gemm_out_kernel(
    const unsigned short* __restrict__ attn, const unsigned short* __restrict__ wot,
    const float* __restrict__ bout, float* __restrict__ out) {
  __shared__ alignas(16) unsigned short sh[16384];
  const int tid = threadIdx.x, w = tid >> 6, l = tid & 63;
  const int l15 = l & 15, l4 = l >> 4;
  const int m0 = blockIdx.x * 128, n0 = blockIdx.y * 128;
  const int wrow = w >> 1, wcol = w & 1;
  const int g_row = l >> 2, g_col = (l & 3) * 8;

  f32x4 acc[4][4] = {};

#define STAGEP(p_) do {                                                        \
    int kk_ = (p_) * 32;                                                       \
    unsigned short* lb0_ = sh + (((p_) & 1) << 13) + (w * 2) * 512;            \
    _Pragma("unroll")                                                          \
    for (int i = 0; i < 2; ++i) {                                              \
      int rb_ = (w * 2 + i) * 16 + g_row;                                      \
      unsigned short* lb_ = lb0_ + i * 512;                                    \
      gload16(attn + (size_t)(m0 + rb_) * 1024 + kk_ + g_col, lb_);            \
      gload16(wot + (size_t)(n0 + rb_) * 1024 + kk_ + g_col, lb_ + 4096);      \
    }                                                                          \
  } while (0)

  STAGEP(0);
  __syncthreads();
  for (int p = 0; p < 32; ++p) {
    if (p + 1 < 32) STAGEP(p + 1);
    const unsigned short* bp = sh + ((p & 1) << 13);
    s16x8 af[4], bfr[4];
#pragma unroll
    for (int g = 0; g < 4; ++g) {
      af[g] = *(const s16x8*)(bp + (wrow * 64 + g * 16 + l15) * 32 + l4 * 8);
      bfr[g] = *(const s16x8*)(bp + 4096 + (wcol * 64 + g * 16 + l15) * 32 + l4 * 8);
    }
#pragma unroll
    for (int rg = 0; rg < 4; ++rg)
#pragma unroll
      for (int cg = 0; cg < 4; ++cg)
        acc[rg][cg] = __builtin_amdgcn_mfma_f32_16x16x32_bf16(af[rg], bfr[cg], acc[rg][cg], 0, 0, 0);
    __syncthreads();
  }
#undef STAGEP

#pragma unroll
  for (int cg = 0; cg < 4; ++cg) {
    int n = n0 + wcol * 64 + cg * 16 + l15;
    float bias = bout[n];
#pragma unroll
    for (int rg = 0; rg < 4; ++rg) {
#pragma unroll
      for (int r = 0; r < 4; ++r) {
        int m = m0 + wrow * 64 + rg * 16 + l4 * 4 + r;
        out[(size_t)m * 1024 + n] = acc[rg][cg][r] + bias;
      }
    }
  }
}

// ---------------- workspace layout (bytes), total 70 MiB ----------------
#define OFF_XHI 0ull
#define OFF_ATT 0ull
#define OFF_XLO 8388608ull
#define OFF_WHI 16777216ull
#define OFF_WLO 23068672ull
#define OFF_WOT 29360128ull
#define OFF_QS  31457280ull
#define OFF_KS  48234496ull
#define OFF_V   65011712ull

extern "C" void kernel_launch(void* const* d_in, const int* in_sizes, int n_in,
                              void* d_out, int out_size, void* d_ws, size_t ws_size,
                              hipStream_t stream) {
  (void)in_sizes; (void)n_in; (void)out_size; (void)ws_size;
  const float* x     = (const float*)d_in[0];
  const float* w_qkv = (const float*)d_in[1];
  const float* b_qkv = (const float*)d_in[2];
  const float* w_out = (const float*)d_in[3];
  const float* b_out = (const float*)d_in[4];
  float* out = (float*)d_out;
  char* ws = (char*)d_ws;

  unsigned short* xhi = (unsigned short*)(ws + OFF_XHI);
  unsigned short* xlo = (unsigned short*)(ws + OFF_XLO);
  unsigned short* whi = (unsigned short*)(ws + OFF_WHI);
  unsigned short* wlo = (unsigned short*)(ws + OFF_WLO);
  unsigned short* wot = (unsigned short*)(ws + OFF_WOT);
  unsigned short* Qsb = (unsigned short*)(ws + OFF_QS);
  unsigned short* Ksb = (unsigned short*)(ws + OFF_KS);
  unsigned short* vbT = (unsigned short*)(ws + OFF_V);
  unsigned short* att = (unsigned short*)(ws + OFF_ATT);

  float* rtab = out;

  split_x_kernel<<<2048, 256, 0, stream>>>(x, xhi, xlo);
  transpose_split_kernel<<<dim3(16, 48), 256, 0, stream>>>(w_qkv, whi, wlo, 3072, 1);
  transpose_split_kernel<<<dim3(16, 16), 256, 0, stream>>>(w_out, wot, nullptr, 1024, 0);
  rope_tab_kernel<<<256, 256, 0, stream>>>(rtab);
  gemm_qkv_kernel<<<768, 512, 0, stream>>>(xhi, xlo, whi, wlo, b_qkv, rtab, Qsb, Ksb, vbT);
  flash_kernel<<<512, 512, 0, stream>>>(Qsb, Ksb, vbT, att);
  gemm_out_kernel<<<dim3(32, 8), 256, 0, stream>>>(att, wot, b_out, out);
}

// Round 21
// 182.153 us; speedup vs baseline: 1.0142x; 1.0142x over previous
//
#include <hip/hip_runtime.h>

// FINAL (r18-verified state, ~182.5 us, absmax 0.03125):
//  1. split_x:          x f32 [4096,1024] -> x_hi, x_lo bf16
//  2. transpose_split:  w_qkv f32 [1024,3072] -> w_hi_t, w_lo_t bf16 [3072,1024] (N-major)
//  3. transpose_split:  w_out f32 [1024,1024] -> w_out_t bf16 [1024,1024]
//  3b. rope_tab:        cos/sin tables [2048][32] f32 -> scratch carved from d_out
//  4. gemm_qkv:   128x128xBK32 dbuf gload_lds pipeline, 512 threads / 8 waves,
//                 balanced 1D grid (Q|K|V), split-precision 3-term product for Q/K,
//                 fused RoPE epilogue (table), V single-term written transposed [bh][d][s].
//  5. flash:      causal attention; 128-row strips, pair-balanced LPT, 8 waves x 16 rows,
//                 double-buffered K/V LDS (1 barrier/tile), V^T staged like K,
//                 defer-max (THR=8), ones-MFMA row-sum, per-cg setprio,
//                 RTE f2bf P pack (trunc-P variant NaNs — r17/r19; keep RTE).
//  6. gemm_out:   BK=32 dbuf gload_lds pipeline, 256 threads.

typedef __attribute__((ext_vector_type(8))) short s16x8;
typedef __attribute__((ext_vector_type(8))) unsigned short u16x8;
typedef __attribute__((ext_vector_type(4))) float f32x4;
typedef __attribute__((ext_vector_type(4))) int i32x4;

#define L2E 1.44269504088896340736f

__device__ __forceinline__ unsigned short f2bf(float f) {
  unsigned int u = __builtin_bit_cast(unsigned int, f);
  u += 0x7FFFu + ((u >> 16) & 1u);
  return (unsigned short)(u >> 16);
}
__device__ __forceinline__ float bf2f(unsigned short h) {
  unsigned int u = ((unsigned int)h) << 16;
  return __builtin_bit_cast(float, u);
}

__device__ __forceinline__ void gload16(const void* g, void* l) {
  __builtin_amdgcn_global_load_lds(
      (const __attribute__((address_space(1))) unsigned int*)g,
      (__attribute__((address_space(3))) unsigned int*)l, 16, 0, 0);
}

// ---------------- 1. split x into hi/lo bf16 ----------------
__global__ __launch_bounds__(256) void split_x_kernel(
    const float* __restrict__ x, unsigned short* __restrict__ xhi,
    unsigned short* __restrict__ xlo) {
  size_t i = ((size_t)blockIdx.x * 256 + threadIdx.x) * 8;
  f32x4 a = *(const f32x4*)(x + i);
  f32x4 c = *(const f32x4*)(x + i + 4);
  u16x8 h, lo;
#pragma unroll
  for (int j = 0; j < 4; ++j) {
    unsigned short hv = f2bf(a[j]);
    h[j] = hv; lo[j] = f2bf(a[j] - bf2f(hv));
    unsigned short hv2 = f2bf(c[j]);
    h[4 + j] = hv2; lo[4 + j] = f2bf(c[j] - bf2f(hv2));
  }
  *(u16x8*)(xhi + i) = h;
  *(u16x8*)(xlo + i) = lo;
}

// ---------------- 2/3. transpose + split weights ----------------
__global__ __launch_bounds__(256) void transpose_split_kernel(
    const float* __restrict__ W, unsigned short* __restrict__ Thi,
    unsigned short* __restrict__ Tlo, int N, int hasLo) {
  __shared__ unsigned short hi[64][72];
  __shared__ unsigned short lo[64][72];
  const int t = threadIdx.x;
  const int k0 = blockIdx.x * 64, n0 = blockIdx.y * 64;
#pragma unroll
  for (int r = 0; r < 16; ++r) {
    int kk = r * 4 + (t >> 6);
    int nn = t & 63;
    float v = W[(size_t)(k0 + kk) * N + n0 + nn];
    unsigned short hv = f2bf(v);
    hi[nn][kk] = hv;
    lo[nn][kk] = f2bf(v - bf2f(hv));
  }
  __syncthreads();
#pragma unroll
  for (int i = 0; i < 2; ++i) {
    int ci = t + i * 256;
    int nn = ci >> 3, kc = (ci & 7) * 8;
    u16x8 vh, vl;
#pragma unroll
    for (int j = 0; j < 8; ++j) { vh[j] = hi[nn][kc + j]; vl[j] = lo[nn][kc + j]; }
    *(u16x8*)(Thi + (size_t)(n0 + nn) * 1024 + k0 + kc) = vh;
    if (hasLo) *(u16x8*)(Tlo + (size_t)(n0 + nn) * 1024 + k0 + kc) = vl;
  }
}

// ---------------- 3b. RoPE cos/sin tables ----------------
__global__ __launch_bounds__(256) void rope_tab_kernel(float* __restrict__ tab) {
  int idx = blockIdx.x * 256 + threadIdx.x;  // 0..65535
  int s = idx >> 5, i = idx & 31;
  float invf = exp2f(-(float)i * 0.4152410118609203f);  // 10000^(-i/32)
  float ang = (float)s * invf;
  tab[idx] = cosf(ang);
  tab[65536 + idx] = sinf(ang);
}

// ---------------- 4. QKV GEMM: 512 threads, 8 waves, BK=32 dbuf ----------------
__global__ __launch_bounds__(512, 4) void gemm_qkv_kernel(
    const unsigned short* __restrict__ xhi, const unsigned short* __restrict__ xlo,
    const unsigned short* __restrict__ whi, const unsigned short* __restrict__ wlo,
    const float* __restrict__ bqkv, const float* __restrict__ ctab,
    unsigned short* __restrict__ Qsb, unsigned short* __restrict__ Ksb,
    unsigned short* __restrict__ vbufT) {
  __shared__ alignas(16) unsigned short sh[32768];
  const int tid = threadIdx.x, w = tid >> 6, l = tid & 63;
  const int l15 = l & 15, l4 = l >> 4;
  const int sid = blockIdx.x;           // 0..767
  const int m0 = (sid & 31) * 128;
  const int n0 = (sid >> 5) * 128;      // 0..2944
  const int wrow = w >> 1, wcol = w & 1;
  const int which = n0 >> 10;           // 0=Q 1=K 2=V (block-uniform)
  const bool isV = (which == 2);
  const float* stab = ctab + 65536;

  f32x4 acc[2][4] = {};

#define STAGEP(p_) do {                                                        \
    int kk_ = (p_) * 32;                                                       \
    unsigned short* bb_ = sh + (((p_) & 1) << 14);                             \
    _Pragma("unroll")                                                          \
    for (int i = 0; i < 4; ++i) {                                              \
      int c_ = w * 4 + i;                                                      \
      if (isV && c_ >= 16) break;                                              \
      int arr_ = c_ >> 3, rc_ = c_ & 7;                                        \
      int row_ = rc_ * 16 + (l >> 2);                                          \
      const unsigned short* src_;                                              \
      if (arr_ == 0)      src_ = xhi + (size_t)(m0 + row_) * 1024;             \
      else if (arr_ == 1) src_ = whi + (size_t)(n0 + row_) * 1024;             \
      else if (arr_ == 2) src_ = wlo + (size_t)(n0 + row_) * 1024;             \
      else                src_ = xlo + (size_t)(m0 + row_) * 1024;             \
      gload16(src_ + kk_ + (l & 3) * 8, bb_ + arr_ * 4096 + rc_ * 512);        \
    }                                                                          \
  } while (0)

  STAGEP(0);
  __syncthreads();
  for (int p = 0; p < 32; ++p) {
    if (p + 1 < 32) STAGEP(p + 1);     // async into buf^1, overlaps compute below
    const unsigned short* bp = sh + ((p & 1) << 14);
    s16x8 af[2], bfr[4];
#pragma unroll
    for (int g = 0; g < 2; ++g)
      af[g] = *(const s16x8*)(bp + (wrow * 32 + g * 16 + l15) * 32 + l4 * 8);
#pragma unroll
    for (int cg = 0; cg < 4; ++cg)
      bfr[cg] = *(const s16x8*)(bp + 4096 + (wcol * 64 + cg * 16 + l15) * 32 + l4 * 8);
#pragma unroll
    for (int rg = 0; rg < 2; ++rg)
#pragma unroll
      for (int cg = 0; cg < 4; ++cg)
        acc[rg][cg] = __builtin_amdgcn_mfma_f32_16x16x32_bf16(af[rg], bfr[cg], acc[rg][cg], 0, 0, 0);
    if (!isV) {
      s16x8 bl[4], al[2];
#pragma unroll
      for (int cg = 0; cg < 4; ++cg)
        bl[cg] = *(const s16x8*)(bp + 8192 + (wcol * 64 + cg * 16 + l15) * 32 + l4 * 8);
#pragma unroll
      for (int g = 0; g < 2; ++g)
        al[g] = *(const s16x8*)(bp + 12288 + (wrow * 32 + g * 16 + l15) * 32 + l4 * 8);
#pragma unroll
      for (int rg = 0; rg < 2; ++rg)
#pragma unroll
        for (int cg = 0; cg < 4; ++cg)
          acc[rg][cg] = __builtin_amdgcn_mfma_f32_16x16x32_bf16(af[rg], bl[cg], acc[rg][cg], 0, 0, 0);
#pragma unroll
      for (int rg = 0; rg < 2; ++rg)
#pragma unroll
        for (int cg = 0; cg < 4; ++cg)
          acc[rg][cg] = __builtin_amdgcn_mfma_f32_16x16x32_bf16(al[rg], bfr[cg], acc[rg][cg], 0, 0, 0);
    }
    __syncthreads();
  }
#undef STAGEP

  // ------- epilogue (LDS transpose -> coalesced stores), 512 threads -------
  const int n_head0 = (n0 & 1023) >> 6;
  const int bb = m0 >> 11;
  const int s_base = m0 & 2047;
  unsigned short* stg = sh;

  if (isV) {
#pragma unroll
    for (int cg = 0; cg < 4; ++cg) {
      int n_local = wcol * 64 + cg * 16 + l15;
      float bias = bqkv[n0 + n_local];
      int swz = (n_local & 7) << 3;
#pragma unroll
      for (int rg = 0; rg < 2; ++rg)
#pragma unroll
        for (int r = 0; r < 4; ++r) {
          int m_local = wrow * 32 + rg * 16 + l4 * 4 + r;
          stg[n_local * 128 + (m_local ^ swz)] = f2bf(acc[rg][cg][r] + bias);
        }
    }
    __syncthreads();
#pragma unroll
    for (int i = 0; i < 4; ++i) {
      int c = i * 512 + tid;
      int n = c >> 4, piece = c & 15;
      int hh = n_head0 + (n >> 6), d = n & 63;
      unsigned short* dst =
          vbufT + ((size_t)(bb * 16 + hh)) * 131072 + d * 2048 + s_base + piece * 8;
      *(i32x4*)dst = *(const i32x4*)(stg + n * 128 + ((piece * 8) ^ ((n & 7) << 3)));
    }
  } else {
    unsigned short* qk = which ? Ksb : Qsb;
    const float sc8 = which ? 1.0f : 8.0f;  // fold score scale sqrt(dk)=8 into Q
#pragma unroll
    for (int cg = 0; cg < 4; ++cg) {
      int n_local = wcol * 64 + cg * 16 + l15;
      int dk = n_local & 63;
      int ih = dk >> 1;
      float bias = bqkv[n0 + n_local];
#pragma unroll
      for (int rg = 0; rg < 2; ++rg)
#pragma unroll
        for (int r = 0; r < 4; ++r) {
          int s = s_base + wrow * 32 + rg * 16 + l4 * 4 + r;
          float v = acc[rg][cg][r] + bias;
          float p = __shfl_xor(v, 1);  // RoPE pair partner dk^1 lives in lane l^1
          float cs = ctab[(s << 5) + ih];
          float sn = stab[(s << 5) + ih];
          float rr = (dk & 1) ? (p * sn + v * cs) : (v * cs - p * sn);
          acc[rg][cg][r] = rr * sc8;
        }
    }
#pragma unroll
    for (int pass = 0; pass < 2; ++pass) {
#pragma unroll
      for (int cg = 0; cg < 4; ++cg) {
        int n_local = wcol * 64 + cg * 16 + l15;
#pragma unroll
        for (int rg = 0; rg < 2; ++rg)
#pragma unroll
          for (int r = 0; r < 4; ++r) {
            int m_local = wrow * 32 + rg * 16 + l4 * 4 + r;
            float rr = acc[rg][cg][r];
            unsigned short hv = f2bf(rr);
            stg[m_local * 128 + n_local] = pass ? f2bf(rr - bf2f(hv)) : hv;
          }
      }
      __syncthreads();
#pragma unroll
      for (int i = 0; i < 4; ++i) {
        int c = i * 512 + tid;
        int hh_l = c >> 10, row = (c >> 3) & 127, piece = c & 7;
        int hh = n_head0 + hh_l;
        unsigned short* dst =
            qk + (((size_t)bb * 16 + hh) * 2048 + s_base + row) * 128 + pass * 64;
        *(i32x4*)(dst + piece * 8) = *(const i32x4*)(stg + row * 128 + hh_l * 64 + piece * 8);
      }
      __syncthreads();
    }
  }
}

// ---------------- 5. flash: dbuf K/V LDS, ones-MFMA row-sum ----------------
__global__ __launch_bounds__(512, 4) void flash_kernel(
    const unsigned short* __restrict__ Qs, const unsigned short* __restrict__ Ks,
    const unsigned short* __restrict__ VbT, unsigned short* __restrict__ attn) {
  __shared__ alignas(16) unsigned short Khi[2][64 * 64];
  __shared__ alignas(16) unsigned short Klo[2][64 * 64];
  __shared__ alignas(16) unsigned short Vt[2][64 * 64];
  __shared__ alignas(16) unsigned short Pl[8][16 * 64];

  const int tid = threadIdx.x;
  const int wv = tid >> 6, l = tid & 63;
  const int l15 = l & 15, l4 = l >> 4;

  const int sid = blockIdx.x;            // 0..511
  const int idx = (sid & 255) >> 5;      // 0..7
  const int strip = (sid >> 8) ? idx : 15 - idx;
  const int hb = sid & 31;
  const int h = hb & 15, b = hb >> 4;
  const int qb = strip * 128;

  const size_t bh = (size_t)(b * 16 + h);
  const unsigned short* Qbase = Qs + bh * 2048 * 128;
  const unsigned short* Kbase = Ks + bh * 2048 * 128;
  const unsigned short* Vbase = VbT + bh * 131072;   // [64 d][2048 s]

  s16x8 qf[2][2];  // [hi/lo][ks]
  {
    int q = qb + wv * 16 + l15;
    const unsigned short* qr = Qbase + (size_t)q * 128;
#pragma unroll
    for (int ks = 0; ks < 2; ++ks) {
      qf[0][ks] = *(const s16x8*)(qr + ks * 32 + l4 * 8);
      qf[1][ks] = *(const s16x8*)(qr + 64 + ks * 32 + l4 * 8);
    }
  }

  s16x8 vones;
#pragma unroll
  for (int j = 0; j < 8; ++j) vones[j] = (short)0x3F80;

  f32x4 acc[4] = {};
  f32x4 accl = {};
  float mrow[4];
#pragma unroll
  for (int r = 0; r < 4; ++r) mrow[r] = -1e38f;

  const int row = tid >> 3;            // 0..63
  const int cb = (tid & 7) * 16;

  i32x4 kh, kl, vv;
#define PREF(kt_) do {                                                        \
    int kv0_ = (kt_) * 64;                                                    \
    const char* s_ = (const char*)(Kbase + (size_t)(kv0_ + row) * 128);       \
    kh = *(const i32x4*)(s_ + cb);  kl = *(const i32x4*)(s_ + 128 + cb);      \
    vv = *(const i32x4*)((const char*)(Vbase + (size_t)row * 2048 + kv0_) + cb); \
  } while (0)

#define STAGE(bf_) do {                                                       \
    int sw = cb ^ ((row & 7) << 4);                                           \
    *(i32x4*)((char*)Khi[bf_] + row * 128 + sw) = kh;                         \
    *(i32x4*)((char*)Klo[bf_] + row * 128 + sw) = kl;                         \
    *(i32x4*)((char*)Vt[bf_] + row * 128 + sw) = vv;                          \
  } while (0)

  const int nt = (qb >> 6) + 2;
  PREF(0);
  STAGE(0);
  if (nt > 1) PREF(1);
  __syncthreads();

  for (int kt = 0; kt < nt; ++kt) {
    const int kv0 = kt * 64;
    const int cur = kt & 1;
    if (kt + 1 < nt) {
      STAGE(cur ^ 1);
      if (kt + 2 < nt) PREF(kt + 2);
    }

    f32x4 sc[4];
#pragma unroll
    for (int cg = 0; cg < 4; ++cg) {
      int kr = cg * 16 + l15;
      int swz = (kr & 7) << 4;
      const char* ph = (const char*)Khi[cur] + kr * 128;
      const char* pl2 = (const char*)Klo[cur] + kr * 128;
      s16x8 kbh[2], kbl[2];
#pragma unroll
      for (int ks = 0; ks < 2; ++ks) {
        int off = (ks * 64 + l4 * 16) ^ swz;
        kbh[ks] = *(const s16x8*)(ph + off);
        kbl[ks] = *(const s16x8*)(pl2 + off);
      }
      __builtin_amdgcn_s_setprio(1);
      f32x4 a = {0.f, 0.f, 0.f, 0.f};
#pragma unroll
      for (int ks = 0; ks < 2; ++ks) {
        a = __builtin_amdgcn_mfma_f32_16x16x32_bf16(qf[0][ks], kbh[ks], a, 0, 0, 0);
        a = __builtin_amdgcn_mfma_f32_16x16x32_bf16(qf[0][ks], kbl[ks], a, 0, 0, 0);
        a = __builtin_amdgcn_mfma_f32_16x16x32_bf16(qf[1][ks], kbh[ks], a, 0, 0, 0);
      }
      __builtin_amdgcn_s_setprio(0);
      sc[cg] = a;
    }

    if (kt >= (qb >> 6)) {
#pragma unroll
      for (int cg = 0; cg < 4; ++cg)
#pragma unroll
        for (int r = 0; r < 4; ++r) {
          int q = qb + wv * 16 + l4 * 4 + r;
          int kv = kv0 + cg * 16 + l15;
          if (kv > q) sc[cg][r] = -1e38f;
        }
    }

    {
      float vmax[4];
      bool cnd = true;
#pragma unroll
      for (int r = 0; r < 4; ++r) {
        float v = fmaxf(fmaxf(sc[0][r], sc[1][r]), fmaxf(sc[2][r], sc[3][r]));
        v = fmaxf(v, __shfl_xor(v, 1));
        v = fmaxf(v, __shfl_xor(v, 2));
        v = fmaxf(v, __shfl_xor(v, 4));
        v = fmaxf(v, __shfl_xor(v, 8));
        vmax[r] = v;
        cnd = cnd && (v <= mrow[r] + 8.0f);
      }
      const bool defer = __all(cnd ? 1 : 0);
      if (!defer) {
#pragma unroll
        for (int r = 0; r < 4; ++r) {
          float mn = fmaxf(mrow[r], vmax[r]);
          float al = exp2f((mrow[r] - mn) * L2E);
          mrow[r] = mn;
          accl[r] *= al;
#pragma unroll
          for (int dg = 0; dg < 4; ++dg) acc[dg][r] *= al;
        }
      }
#pragma unroll
      for (int cg = 0; cg < 4; ++cg)
#pragma unroll
        for (int r = 0; r < 4; ++r)
          sc[cg][r] = exp2f((sc[cg][r] - mrow[r]) * L2E);
      // P pack: RTE f2bf (trunc variant NaNs — verified r17/r19; keep RTE)
#pragma unroll
      for (int cg = 0; cg < 4; ++cg)
#pragma unroll
        for (int r = 0; r < 4; ++r) {
          int roww = l4 * 4 + r;
          int colb = (cg * 16 + l15) * 2;
          int addr = roww * 128 + (colb ^ ((roww & 7) << 4));
          *(unsigned short*)((char*)Pl[wv] + addr) = f2bf(sc[cg][r]);
        }
    }

    {
      s16x8 pf[2];
      int swz = (l15 & 7) << 4;
#pragma unroll
      for (int kc = 0; kc < 2; ++kc)
        pf[kc] = *(const s16x8*)((const char*)Pl[wv] + l15 * 128 + ((kc * 64 + l4 * 16) ^ swz));
      __builtin_amdgcn_s_setprio(1);
#pragma unroll
      for (int dg = 0; dg < 4; ++dg) {
        int dr = dg * 16 + l15;
        int swzd = (dr & 7) << 4;
#pragma unroll
        for (int kc = 0; kc < 2; ++kc) {
          s16x8 vf = *(const s16x8*)((const char*)Vt[cur] + dr * 128 + ((kc * 64 + l4 * 16) ^ swzd));
          acc[dg] = __builtin_amdgcn_mfma_f32_16x16x32_bf16(pf[kc], vf, acc[dg], 0, 0, 0);
        }
      }
#pragma unroll
      for (int kc = 0; kc < 2; ++kc)
        accl = __builtin_amdgcn_mfma_f32_16x16x32_bf16(pf[kc], vones, accl, 0, 0, 0);
      __builtin_amdgcn_s_setprio(0);
    }
    __syncthreads();
  }
#undef PREF
#undef STAGE

  {
    unsigned short* stg = (unsigned short*)Pl;
#pragma unroll
    for (int r = 0; r < 4; ++r) {
      float inv = 1.0f / accl[r];
      int row_local = wv * 16 + l4 * 4 + r;
#pragma unroll
      for (int dg = 0; dg < 4; ++dg)
        stg[row_local * 64 + dg * 16 + l15] = f2bf(acc[dg][r] * inv);
    }
    __syncthreads();
#pragma unroll
    for (int i = 0; i < 2; ++i) {
      int c = i * 512 + tid;
      int rw = c >> 3, piece = c & 7;
      unsigned short* dst = attn + ((size_t)(b * 2048 + qb + rw)) * 1024 + h * 64;
      *(i32x4*)(dst + piece * 8) = *(const i32x4*)(stg + rw * 64 + piece * 8);
    }
  }
}

// ---------------- 6. output projection: BK=32 dbuf ----------------
__global__ __launch_bounds__(256) void gemm_out_kernel(
    const unsigned short* __restrict__ attn, const unsigned short* __restrict__ wot,
    const float* __restrict__ bout, float* __restrict__ out) {
  __shared__ alignas(16) unsigned short sh[16384];
  const int tid = threadIdx.x, w = tid >> 6, l = tid & 63;
  const int l15 = l & 15, l4 = l >> 4;
  const int m0 = blockIdx.x * 128, n0 = blockIdx.y * 128;
  const int wrow = w >> 1, wcol = w & 1;
  const int g_row = l >> 2, g_col = (l & 3) * 8;

  f32x4 acc[4][4] = {};

#define STAGEP(p_) do {                                                        \
    int kk_ = (p_) * 32;                                                       \
    unsigned short* lb0_ = sh + (((p_) & 1) << 13) + (w * 2) * 512;            \
    _Pragma("unroll")                                                          \
    for (int i = 0; i < 2; ++i) {                                              \
      int rb_ = (w * 2 + i) * 16 + g_row;                                      \
      unsigned short* lb_ = lb0_ + i * 512;                                    \
      gload16(attn + (size_t)(m0 + rb_) * 1024 + kk_ + g_col, lb_);            \
      gload16(wot + (size_t)(n0 + rb_) * 1024 + kk_ + g_col, lb_ + 4096);      \
    }                                                                          \
  } while (0)

  STAGEP(0);
  __syncthreads();
  for (int p = 0; p < 32; ++p) {
    if (p + 1 < 32) STAGEP(p + 1);
    const unsigned short* bp = sh + ((p & 1) << 13);
    s16x8 af[4], bfr[4];
#pragma unroll
    for (int g = 0; g < 4; ++g) {
      af[g] = *(const s16x8*)(bp + (wrow * 64 + g * 16 + l15) * 32 + l4 * 8);
      bfr[g] = *(const s16x8*)(bp + 4096 + (wcol * 64 + g * 16 + l15) * 32 + l4 * 8);
    }
#pragma unroll
    for (int rg = 0; rg < 4; ++rg)
#pragma unroll
      for (int cg = 0; cg < 4; ++cg)
        acc[rg][cg] = __builtin_amdgcn_mfma_f32_16x16x32_bf16(af[rg], bfr[cg], acc[rg][cg], 0, 0, 0);
    __syncthreads();
  }
#undef STAGEP

#pragma unroll
  for (int cg = 0; cg < 4; ++cg) {
    int n = n0 + wcol * 64 + cg * 16 + l15;
    float bias = bout[n];
#pragma unroll
    for (int rg = 0; rg < 4; ++rg) {
#pragma unroll
      for (int r = 0; r < 4; ++r) {
        int m = m0 + wrow * 64 + rg * 16 + l4 * 4 + r;
        out[(size_t)m * 1024 + n] = acc[rg][cg][r] + bias;
      }
    }
  }
}

// ---------------- workspace layout (bytes), total 70 MiB ----------------
#define OFF_XHI 0ull
#define OFF_ATT 0ull
#define OFF_XLO 8388608ull
#define OFF_WHI 16777216ull
#define OFF_WLO 23068672ull
#define OFF_WOT 29360128ull
#define OFF_QS  31457280ull
#define OFF_KS  48234496ull
#define OFF_V   65011712ull

extern "C" void kernel_launch(void* const* d_in, const int* in_sizes, int n_in,
                              void* d_out, int out_size, void* d_ws, size_t ws_size,
                              hipStream_t stream) {
  (void)in_sizes; (void)n_in; (void)out_size; (void)ws_size;
  const float* x     = (const float*)d_in[0];
  const float* w_qkv = (const float*)d_in[1];
  const float* b_qkv = (const float*)d_in[2];
  const float* w_out = (const float*)d_in[3];
  const float* b_out = (const float*)d_in[4];
  float* out = (float*)d_out;
  char* ws = (char*)d_ws;

  unsigned short* xhi = (unsigned short*)(ws + OFF_XHI);
  unsigned short* xlo = (unsigned short*)(ws + OFF_XLO);
  unsigned short* whi = (unsigned short*)(ws + OFF_WHI);
  unsigned short* wlo = (unsigned short*)(ws + OFF_WLO);
  unsigned short* wot = (unsigned short*)(ws + OFF_WOT);
  unsigned short* Qsb = (unsigned short*)(ws + OFF_QS);
  unsigned short* Ksb = (unsigned short*)(ws + OFF_KS);
  unsigned short* vbT = (unsigned short*)(ws + OFF_V);
  unsigned short* att = (unsigned short*)(ws + OFF_ATT);

  // RoPE tables live in the first 512 KB of d_out (fully overwritten by gemm_out later)
  float* rtab = out;

  split_x_kernel<<<2048, 256, 0, stream>>>(x, xhi, xlo);
  transpose_split_kernel<<<dim3(16, 48), 256, 0, stream>>>(w_qkv, whi, wlo, 3072, 1);
  transpose_split_kernel<<<dim3(16, 16), 256, 0, stream>>>(w_out, wot, nullptr, 1024, 0);
  rope_tab_kernel<<<256, 256, 0, stream>>>(rtab);
  gemm_qkv_kernel<<<768, 512, 0, stream>>>(xhi, xlo, whi, wlo, b_qkv, rtab, Qsb, Ksb, vbT);
  flash_kernel<<<512, 512, 0, stream>>>(Qsb, Ksb, vbT, att);
  gemm_out_kernel<<<dim3(32, 8), 256, 0, stream>>>(att, wot, b_out, out);
}